// Round 4
// baseline (130.265 us; speedup 1.0000x reference)
//
#include <hip/hip_runtime.h>

// SNNLinear, exact-trajectory i8-digit MFMA. Round 22 = R21 + register
// software-pipelining.
// R21 post-mortem: spill gone (WRITE 26 MB, FETCH 22 MB), gemm_scan 42.9us
// but MfmaUtil 25% vs 15.2us MFMA floor -> load-latency exposed: the kt
// loop loaded all 11 fragments then consumed them immediately; with only
// 2 waves/SIMD a full L2/L3 round-trip (~400-600cy) per kt is unhidden
// against 571cy of MFMA.
// R22: A fragments double-buffered in registers (afA/afB, prefetched one
// full kt ahead -> covered by 28 MFMAs); B fragments self-overwrite
// prefetched (bf[p] reloaded for kt+1 right after copying to a local,
// before p's 7 MFMAs). Double buffer selected by MANUAL 2-step unroll
// with NAMED arrays (rule: runtime-indexed ext_vector arrays -> scratch,
// the R20 failure). Regs: acc 112 (AGPR) + af 56 + bf 16 + temps ~40
// fits 256 @ launch_bounds(64,2).
// Structure otherwise R21: one wave per block = (b, n16): 112m x 16n x
// 1024k x 4 planes, direct global->VGPR (A8/Bt fragment-tiled), zero
// barriers, LDS = 12.8 KB du transpose only, scan tail overlaps other
// waves' MFMA phases. bid = ng*64 + b -> bid%8 = b%8 XCD A-locality.
// Math identical to R19/R20/R21 (passed): exact 0/1 A, 4 balanced
// base-256 i8 planes of round(W*2^28), mfma_i32_16x16x64_i8 exact,
// i64 Horner -> exact f64 du -> f64 scan verbatim.
// Outputs: ss[100,64,1024] | mem_out[64,1024] | hat_s[64,1024]
// ws: [0, 7.34M) A8 (b-major, t-pad 112) ; [7.34M, 11.53M) Bt (4 planes)

typedef __attribute__((ext_vector_type(4))) int int4v;

#define T_STEPS 100
#define T_PAD   112
#define BO      65536
#define K_DIM   1024
#define A8_OFF  0
#define BT_OFF  7340032      // 64*112*1024

// ---- prepass (R19 verbatim): spikes -> A8 (b-major, t-padded, tiled);
//               W -> Bt 4 balanced base-256 i8 planes ----
__global__ __launch_bounds__(256)
void prepass(const float* __restrict__ S, const float* __restrict__ W,
             signed char* __restrict__ A8, signed char* __restrict__ Bt) {
    const int wave = blockIdx.x * 4 + (threadIdx.x >> 6);  // 0..8191
    const int lane = threadIdx.x & 63;
    const int r16 = lane & 15, quad = lane >> 4;

    if (wave < 7168) {
        // A tile: wave = b*112 + jt*16 + k64 ; rows t = jt*16 + r16
        const int b   = wave / 112;
        const int rem = wave - b * 112;
        const int jt  = rem >> 4, k64 = rem & 15;
        const int t   = jt * 16 + r16;
        union { signed char c[16]; int4v v; } u;
        if (t < T_STEPS) {
            const float* sp = S + ((size_t)t * 64 + b) * K_DIM + k64 * 64 + quad * 16;
            const float4 s0 = *(const float4*)(sp);
            const float4 s1 = *(const float4*)(sp + 4);
            const float4 s2 = *(const float4*)(sp + 8);
            const float4 s3 = *(const float4*)(sp + 12);
            const float sv[16] = {s0.x,s0.y,s0.z,s0.w, s1.x,s1.y,s1.z,s1.w,
                                  s2.x,s2.y,s2.z,s2.w, s3.x,s3.y,s3.z,s3.w};
#pragma unroll
            for (int e = 0; e < 16; ++e) u.c[e] = (signed char)sv[e];  // exact 0/1
        } else {
#pragma unroll
            for (int e = 0; e < 16; ++e) u.c[e] = 0;                   // t-pad
        }
        *(int4v*)(A8 + (size_t)wave * 1024 + lane * 16) = u.v;
    } else {
        const int t2 = wave - 7168;                 // 0..1023
        const int n16 = t2 >> 4, k64 = t2 & 15;
        const int n = n16 * 16 + r16;
        const float* wp = W + (size_t)n * K_DIM + k64 * 64 + quad * 16;
        const float4 w0 = *(const float4*)(wp);
        const float4 w1 = *(const float4*)(wp + 4);
        const float4 w2 = *(const float4*)(wp + 8);
        const float4 w3 = *(const float4*)(wp + 12);
        const float wv[16] = {w0.x,w0.y,w0.z,w0.w, w1.x,w1.y,w1.z,w1.w,
                              w2.x,w2.y,w2.z,w2.w, w3.x,w3.y,w3.z,w3.w};
        union { signed char c[16]; int4v v; } u[4];
#pragma unroll
        for (int e = 0; e < 16; ++e) {
            long long q = llrint((double)wv[e] * 0x1p28);   // |q| < 2^31
#pragma unroll
            for (int p = 0; p < 3; ++p) {
                const int d = (int)(((q + 128) & 255) - 128);  // [-128,127]
                u[p].c[e] = (signed char)d;
                q = (q - d) >> 8;                              // exact
            }
            u[3].c[e] = (signed char)q;                        // |d3| <= ~88
        }
        signed char* base = Bt + (size_t)(n16 * 16 + k64) * 4 * 1024 + lane * 16;
#pragma unroll
        for (int p = 0; p < 4; ++p)
            *(int4v*)(base + (size_t)p * 1024) = u[p].v;
    }
}

// ---- fused GEMM + scan, one wave per block, register-pipelined. ----

// one kt step: compute from AFC, prefetch A(kt+1) into AFN, bf self-prefetch
#define GEMM_STEP(AFC, AFN, KT)                                               \
    {                                                                         \
        if ((KT) < 15) {                                                      \
            _Pragma("unroll")                                                 \
            for (int i = 0; i < 7; ++i)                                       \
                AFN[i] = *(const int4v*)(abase +                              \
                              (size_t)(i * 16 + (KT) + 1) * 1024);            \
        }                                                                     \
        _Pragma("unroll")                                                     \
        for (int p = 0; p < 4; ++p) {                                         \
            const int4v bcur = bf[p];                                         \
            if ((KT) < 15)                                                    \
                bf[p] = *(const int4v*)(bbase +                               \
                             (size_t)(((KT) + 1) * 4 + p) * 1024);            \
            _Pragma("unroll")                                                 \
            for (int i = 0; i < 7; ++i)                                       \
                acc[i][p] = __builtin_amdgcn_mfma_i32_16x16x64_i8(            \
                    AFC[i], bcur, acc[i][p], 0, 0, 0);                        \
        }                                                                     \
    }

__global__ __launch_bounds__(64, 2)
void gemm_scan(const signed char* __restrict__ A8,
               const signed char* __restrict__ Bt,
               const float* __restrict__ bias,
               const float* __restrict__ mem0,
               float* __restrict__ out) {
    __shared__ double dulds[T_STEPS * 16];       // 12800 B

    const int bid = blockIdx.x;                  // 0..4095
    const int ng  = bid >> 6;                    // n16 tile 0..63
    const int b   = bid & 63;                    // batch row; bid%8 = b%8 -> XCD locality

    const int lane = threadIdx.x & 63;
    const int quad = lane >> 4, r16 = lane & 15;

    // fragment bases (1 KB chunks, lane-linear 16B/lane)
    const signed char* abase = A8 + (size_t)b * T_PAD * 1024 + lane * 16;
    const signed char* bbase = Bt + (size_t)ng * 65536 + lane * 16;

    int4v afA[7], afB[7], bf[4];
    int4v acc[7][4] = {};

    // prologue: kt=0 fragments
#pragma unroll
    for (int i = 0; i < 7; ++i)
        afA[i] = *(const int4v*)(abase + (size_t)(i * 16) * 1024);
#pragma unroll
    for (int p = 0; p < 4; ++p)
        bf[p] = *(const int4v*)(bbase + (size_t)p * 1024);

    for (int kt = 0; kt < 16; kt += 2) {
        GEMM_STEP(afA, afB, kt);       // compute kt,   prefetch kt+1 -> afB
        GEMM_STEP(afB, afA, kt + 1);   // compute kt+1, prefetch kt+2 -> afA
    }

    // exact i64 Horner -> f64 du -> LDS transpose (row t, col r16)
    const double bd = (double)bias[ng * 16 + r16];
#pragma unroll
    for (int i = 0; i < 7; ++i)
#pragma unroll
        for (int e = 0; e < 4; ++e) {
            const int t = i * 16 + quad * 4 + e;
            if (t < T_STEPS) {
                long long v = (long long)acc[i][3][e];
                v = v * 256 + (long long)acc[i][2][e];
                v = v * 256 + (long long)acc[i][1][e];
                v = v * 256 + (long long)acc[i][0][e];   // exact, |v| < 2^42
                dulds[t * 16 + r16] = (double)v * 0x1p-28 + bd;
            }
        }
    __syncthreads();   // single wave: compiles to a waitcnt, no scheduling cost

    // membrane scan (R16 math verbatim, exact f64 du): 16 lanes, 16 columns.
    if (lane < 16) {
        const int bo = b * 1024 + ng * 16 + lane;
        double m = (double)mem0[bo];
        double cnt = 0.0;
        double d[4];
#pragma unroll
        for (int u = 0; u < 4; ++u) d[u] = dulds[u * 16 + lane];
        for (int g = 0; g < 25; ++g) {
            double dn[4];
            if (g + 1 < 25) {
#pragma unroll
                for (int u = 0; u < 4; ++u) dn[u] = dulds[((g + 1) * 4 + u) * 16 + lane];
            }
#pragma unroll
            for (int u = 0; u < 4; ++u) {
                m += d[u];
                const double s = (m > 15.0) ? 1.0 : 0.0;
                m = fmin(fmax(m, 0.0), 15.0);
                out[(size_t)(g * 4 + u) * BO + bo] = (float)s;
                cnt += s;
                m -= m * s;
            }
            if (g + 1 < 25) {
#pragma unroll
                for (int u = 0; u < 4; ++u) d[u] = dn[u];
            }
        }
        out[(size_t)T_STEPS * BO + bo] = (float)m;
        out[(size_t)(T_STEPS + 1) * BO + bo] = (float)(cnt * 0.01);
    }
}

extern "C" void kernel_launch(void* const* d_in, const int* in_sizes, int n_in,
                              void* d_out, int out_size, void* d_ws, size_t ws_size,
                              hipStream_t stream) {
    const float* spikes = (const float*)d_in[0];  // [100,64,1024]
    const float* mem    = (const float*)d_in[1];  // [64,1024]
    // d_in[2] = hat_spikes: dead in forward
    const float* W      = (const float*)d_in[3];  // [1024,1024]
    const float* b      = (const float*)d_in[4];  // [1024]
    float* out = (float*)d_out;
    signed char* A8 = (signed char*)d_ws + A8_OFF;
    signed char* Bt = (signed char*)d_ws + BT_OFF;

    prepass<<<dim3(2048), 256, 0, stream>>>(spikes, W, A8, Bt);
    gemm_scan<<<dim3(4096), 64, 0, stream>>>(A8, Bt, b, mem, out);
}

// Round 5
// 124.531 us; speedup vs baseline: 1.0460x; 1.0460x over previous
//
#include <hip/hip_runtime.h>

// SNNLinear, exact-trajectory i8-digit MFMA. Round 23 = intra-wave task
// pipelining (scan(i) overlapped with GEMM(i+1) in the SAME wave).
// R22 post-mortem: reg-pipelining of loads was neutral (MfmaUtil flat 24%)
// -> load latency is not the binder. Budget: MFMA floor 15.2us, GEMM phase
// ~22us at ~70% pipe; the other ~20us is the epilogue/scan region where
// MFMA sits idle: 100-step dependent f64 chain on 16/64 lanes, aligned
// across all waves of a generation (nothing left to overlap).
// R23: each block runs TWO tasks (same b, ngB = ngA+32; grid 2048 = all
// 8 blocks/CU resident, no generation churn). Per kt of task B: issue
// af/bf loads -> one 4-step scan group of task A (dependent f64 covers
// the load flight) -> 28 MFMAs in s_setprio(1) (T5: waves now have
// MFMA-vs-VALU role diversity). Only the last task's scan is exposed.
// Math identical to R19..R22 (all passed): exact 0/1 A, 4 balanced
// base-256 i8 planes of round(W*2^28), mfma_i32_16x16x64_i8 exact,
// i64 Horner -> exact f64 du -> f64 scan verbatim.
// Outputs: ss[100,64,1024] | mem_out[64,1024] | hat_s[64,1024]
// ws: [0, 7.34M) A8 (b-major, t-pad 112) ; [7.34M, 11.53M) Bt (4 planes)

typedef __attribute__((ext_vector_type(4))) int int4v;

#define T_STEPS 100
#define T_PAD   112
#define BO      65536
#define K_DIM   1024
#define A8_OFF  0
#define BT_OFF  7340032      // 64*112*1024

// ---- prepass (R19 verbatim): spikes -> A8 (b-major, t-padded, tiled);
//               W -> Bt 4 balanced base-256 i8 planes ----
__global__ __launch_bounds__(256)
void prepass(const float* __restrict__ S, const float* __restrict__ W,
             signed char* __restrict__ A8, signed char* __restrict__ Bt) {
    const int wave = blockIdx.x * 4 + (threadIdx.x >> 6);  // 0..8191
    const int lane = threadIdx.x & 63;
    const int r16 = lane & 15, quad = lane >> 4;

    if (wave < 7168) {
        // A tile: wave = b*112 + jt*16 + k64 ; rows t = jt*16 + r16
        const int b   = wave / 112;
        const int rem = wave - b * 112;
        const int jt  = rem >> 4, k64 = rem & 15;
        const int t   = jt * 16 + r16;
        union { signed char c[16]; int4v v; } u;
        if (t < T_STEPS) {
            const float* sp = S + ((size_t)t * 64 + b) * K_DIM + k64 * 64 + quad * 16;
            const float4 s0 = *(const float4*)(sp);
            const float4 s1 = *(const float4*)(sp + 4);
            const float4 s2 = *(const float4*)(sp + 8);
            const float4 s3 = *(const float4*)(sp + 12);
            const float sv[16] = {s0.x,s0.y,s0.z,s0.w, s1.x,s1.y,s1.z,s1.w,
                                  s2.x,s2.y,s2.z,s2.w, s3.x,s3.y,s3.z,s3.w};
#pragma unroll
            for (int e = 0; e < 16; ++e) u.c[e] = (signed char)sv[e];  // exact 0/1
        } else {
#pragma unroll
            for (int e = 0; e < 16; ++e) u.c[e] = 0;                   // t-pad
        }
        *(int4v*)(A8 + (size_t)wave * 1024 + lane * 16) = u.v;
    } else {
        const int t2 = wave - 7168;                 // 0..1023
        const int n16 = t2 >> 4, k64 = t2 & 15;
        const int n = n16 * 16 + r16;
        const float* wp = W + (size_t)n * K_DIM + k64 * 64 + quad * 16;
        const float4 w0 = *(const float4*)(wp);
        const float4 w1 = *(const float4*)(wp + 4);
        const float4 w2 = *(const float4*)(wp + 8);
        const float4 w3 = *(const float4*)(wp + 12);
        const float wv[16] = {w0.x,w0.y,w0.z,w0.w, w1.x,w1.y,w1.z,w1.w,
                              w2.x,w2.y,w2.z,w2.w, w3.x,w3.y,w3.z,w3.w};
        union { signed char c[16]; int4v v; } u[4];
#pragma unroll
        for (int e = 0; e < 16; ++e) {
            long long q = llrint((double)wv[e] * 0x1p28);   // |q| < 2^31
#pragma unroll
            for (int p = 0; p < 3; ++p) {
                const int d = (int)(((q + 128) & 255) - 128);  // [-128,127]
                u[p].c[e] = (signed char)d;
                q = (q - d) >> 8;                              // exact
            }
            u[3].c[e] = (signed char)q;                        // |d3| <= ~88
        }
        signed char* base = Bt + (size_t)(n16 * 16 + k64) * 4 * 1024 + lane * 16;
#pragma unroll
        for (int p = 0; p < 4; ++p)
            *(int4v*)(base + (size_t)p * 1024) = u[p].v;
    }
}

// ---- fused GEMM + scan, one wave per block, two tasks per block. ----

// load fragments for one kt into af/bf (declared in enclosing scope)
#define GEMM_LOAD(BB, KT)                                                     \
    {                                                                         \
        _Pragma("unroll")                                                     \
        for (int i = 0; i < 7; ++i)                                           \
            af[i] = *(const int4v*)(abase + (size_t)(i * 16 + (KT)) * 1024);  \
        _Pragma("unroll")                                                     \
        for (int p = 0; p < 4; ++p)                                           \
            bf[p] = *(const int4v*)((BB) + (size_t)((KT) * 4 + p) * 1024);    \
    }

// 28 MFMAs of one kt, setprio-wrapped (T5)
#define GEMM_MFMA()                                                           \
    {                                                                         \
        __builtin_amdgcn_s_setprio(1);                                        \
        _Pragma("unroll")                                                     \
        for (int p = 0; p < 4; ++p)                                           \
            _Pragma("unroll")                                                 \
            for (int i = 0; i < 7; ++i)                                       \
                acc[i][p] = __builtin_amdgcn_mfma_i32_16x16x64_i8(            \
                    af[i], bf[p], acc[i][p], 0, 0, 0);                        \
        __builtin_amdgcn_s_setprio(0);                                        \
    }

// exact i64 Horner -> f64 du -> LDS transpose (row t, col r16)
#define HORNER(NG)                                                            \
    {                                                                         \
        const double bd = (double)bias[(NG) * 16 + r16];                      \
        _Pragma("unroll")                                                     \
        for (int i = 0; i < 7; ++i)                                           \
            _Pragma("unroll")                                                 \
            for (int e = 0; e < 4; ++e) {                                     \
                const int t = i * 16 + quad * 4 + e;                          \
                if (t < T_STEPS) {                                            \
                    long long v = (long long)acc[i][3][e];                    \
                    v = v * 256 + (long long)acc[i][2][e];                    \
                    v = v * 256 + (long long)acc[i][1][e];                    \
                    v = v * 256 + (long long)acc[i][0][e];                    \
                    dulds[t * 16 + r16] = (double)v * 0x1p-28 + bd;           \
                }                                                             \
            }                                                                 \
    }

// one 4-step scan group (R16 math verbatim); only lane<16 active
#define SCAN_GROUP(M, CNT, BO_, G)                                            \
    if (lane < 16) {                                                          \
        _Pragma("unroll")                                                     \
        for (int u = 0; u < 4; ++u) {                                         \
            M += dulds[((G) * 4 + u) * 16 + lane];                            \
            const double s_ = (M > 15.0) ? 1.0 : 0.0;                         \
            M = fmin(fmax(M, 0.0), 15.0);                                     \
            out[(size_t)((G) * 4 + u) * BO + (BO_)] = (float)s_;              \
            CNT += s_;                                                        \
            M -= M * s_;                                                      \
        }                                                                     \
    }

#define SCAN_TAIL(M, CNT, BO_)                                                \
    if (lane < 16) {                                                          \
        out[(size_t)T_STEPS * BO + (BO_)] = (float)(M);                       \
        out[(size_t)(T_STEPS + 1) * BO + (BO_)] = (float)((CNT) * 0.01);      \
    }

__global__ __launch_bounds__(64, 2)
void gemm_scan(const signed char* __restrict__ A8,
               const signed char* __restrict__ Bt,
               const float* __restrict__ bias,
               const float* __restrict__ mem0,
               float* __restrict__ out) {
    __shared__ double dulds[T_STEPS * 16];       // 12800 B

    const int bid = blockIdx.x;                  // 0..2047
    const int ngA = bid >> 6;                    // 0..31
    const int b   = bid & 63;                    // bid%8 = b%8 -> XCD A-locality
    const int ngB = ngA + 32;                    // same b -> A panel L2-warm

    const int lane = threadIdx.x & 63;
    const int quad = lane >> 4, r16 = lane & 15;

    const signed char* abase  = A8 + (size_t)b * T_PAD * 1024 + lane * 16;
    const signed char* bbaseA = Bt + (size_t)ngA * 65536 + lane * 16;
    const signed char* bbaseB = Bt + (size_t)ngB * 65536 + lane * 16;

    int4v acc[7][4];
    int4v af[7], bf[4];

    // ---- task A GEMM (R21 structure verbatim) ----
#pragma unroll
    for (int i = 0; i < 7; ++i)
#pragma unroll
        for (int p = 0; p < 4; ++p) acc[i][p] = (int4v){0, 0, 0, 0};
    for (int kt = 0; kt < 16; ++kt) {
        GEMM_LOAD(bbaseA, kt);
        GEMM_MFMA();
    }
    HORNER(ngA);
    __syncthreads();

    // scan-A state
    const int boA = b * 1024 + ngA * 16 + r16;
    double mA = (double)mem0[boA];               // lanes>=16 read duplicates, unused
    double cntA = 0.0;

    // ---- interleaved: GEMM(B) kt 0..15  ||  scan(A) groups 0..15 ----
#pragma unroll
    for (int i = 0; i < 7; ++i)
#pragma unroll
        for (int p = 0; p < 4; ++p) acc[i][p] = (int4v){0, 0, 0, 0};
    for (int kt = 0; kt < 16; ++kt) {
        GEMM_LOAD(bbaseB, kt);                   // loads in flight...
        SCAN_GROUP(mA, cntA, boA, kt);           // ...covered by scan chain
        GEMM_MFMA();
    }
    // remaining scan-A groups 16..24
    for (int g = 16; g < 25; ++g) {
        SCAN_GROUP(mA, cntA, boA, g);
    }
    SCAN_TAIL(mA, cntA, boA);
    __syncthreads();                             // scan-A LDS reads drained
    HORNER(ngB);
    __syncthreads();

    // ---- scan B (exposed tail, ~2us chip-wide) ----
    const int boB = b * 1024 + ngB * 16 + r16;
    double mB = (double)mem0[boB];
    double cntB = 0.0;
    for (int g = 0; g < 25; ++g) {
        SCAN_GROUP(mB, cntB, boB, g);
    }
    SCAN_TAIL(mB, cntB, boB);
}

extern "C" void kernel_launch(void* const* d_in, const int* in_sizes, int n_in,
                              void* d_out, int out_size, void* d_ws, size_t ws_size,
                              hipStream_t stream) {
    const float* spikes = (const float*)d_in[0];  // [100,64,1024]
    const float* mem    = (const float*)d_in[1];  // [64,1024]
    // d_in[2] = hat_spikes: dead in forward
    const float* W      = (const float*)d_in[3];  // [1024,1024]
    const float* b      = (const float*)d_in[4];  // [1024]
    float* out = (float*)d_out;
    signed char* A8 = (signed char*)d_ws + A8_OFF;
    signed char* Bt = (signed char*)d_ws + BT_OFF;

    prepass<<<dim3(2048), 256, 0, stream>>>(spikes, W, A8, Bt);
    gemm_scan<<<dim3(2048), 64, 0, stream>>>(A8, Bt, b, mem, out);
}